// Round 4
// baseline (493.072 us; speedup 1.0000x reference)
//
#include <hip/hip_runtime.h>
#include <hip/hip_bf16.h>
#include <math.h>

#define NTOK    16384
#define DMODEL  1024
#define HN      4
#define NBUCKET 4096
#define ASSOC   4
#define DKEY    64
#define DVAL    128
#define DTAG    32
#define NBITS   12
#define EPSV    1e-6f

typedef __bf16 bf16x8 __attribute__((ext_vector_type(8)));
typedef float  f32x4  __attribute__((ext_vector_type(4)));
typedef float  f32x2  __attribute__((ext_vector_type(2)));

__device__ __forceinline__ unsigned short f2bf_raw(float f) {
    __hip_bfloat16 h = __float2bfloat16(f);
    return *(unsigned short*)&h;
}

// ---------------- MFMA GEMM 128x128 tile: C[M,N] = A[M,K] @ B[N,K]^T ----------------
__global__ __launch_bounds__(256) void gemm_mfma(const float* __restrict__ A,
                                                 const float* __restrict__ B,
                                                 float* __restrict__ C,
                                                 int M, int N, int K) {
    __shared__ __align__(16) unsigned short As[4][128][8];
    __shared__ __align__(16) unsigned short Bs[4][128][8];
    const int t    = threadIdx.x;
    const int lane = t & 63;
    const int w    = t >> 6;
    const int wm   = (w & 1) * 64;
    const int wn   = (w >> 1) * 64;
    const int bm   = blockIdx.x * 128;
    const int bn   = blockIdx.y * 128;

    const int srow = t & 127;
    const int skg  = t >> 7;
    const float* Ap = A + (size_t)(bm + srow) * K;
    const float* Bp = B + (size_t)(bn + srow) * K;

    const int fr = lane & 15;
    const int kq = lane >> 4;

    f32x4 acc[4][4] = {};

    for (int k0 = 0; k0 < K; k0 += 32) {
        #pragma unroll
        for (int ii = 0; ii < 2; ++ii) {
            const int kg = skg + ii * 2;
            const float4 a0 = *(const float4*)(Ap + k0 + kg * 8);
            const float4 a1 = *(const float4*)(Ap + k0 + kg * 8 + 4);
            const float4 b0 = *(const float4*)(Bp + k0 + kg * 8);
            const float4 b1 = *(const float4*)(Bp + k0 + kg * 8 + 4);
            unsigned short* da = &As[kg][srow][0];
            da[0] = f2bf_raw(a0.x); da[1] = f2bf_raw(a0.y);
            da[2] = f2bf_raw(a0.z); da[3] = f2bf_raw(a0.w);
            da[4] = f2bf_raw(a1.x); da[5] = f2bf_raw(a1.y);
            da[6] = f2bf_raw(a1.z); da[7] = f2bf_raw(a1.w);
            unsigned short* db = &Bs[kg][srow][0];
            db[0] = f2bf_raw(b0.x); db[1] = f2bf_raw(b0.y);
            db[2] = f2bf_raw(b0.z); db[3] = f2bf_raw(b0.w);
            db[4] = f2bf_raw(b1.x); db[5] = f2bf_raw(b1.y);
            db[6] = f2bf_raw(b1.z); db[7] = f2bf_raw(b1.w);
        }
        __syncthreads();
        bf16x8 af[4], bfv[4];
        #pragma unroll
        for (int i = 0; i < 4; ++i) af[i]  = *(const bf16x8*)&As[kq][wm + i * 16 + fr][0];
        #pragma unroll
        for (int j = 0; j < 4; ++j) bfv[j] = *(const bf16x8*)&Bs[kq][wn + j * 16 + fr][0];
        #pragma unroll
        for (int i = 0; i < 4; ++i)
            #pragma unroll
            for (int j = 0; j < 4; ++j)
                acc[i][j] = __builtin_amdgcn_mfma_f32_16x16x32_bf16(af[i], bfv[j], acc[i][j], 0, 0, 0);
        __syncthreads();
    }
    #pragma unroll
    for (int i = 0; i < 4; ++i)
        #pragma unroll
        for (int j = 0; j < 4; ++j)
            #pragma unroll
            for (int r = 0; r < 4; ++r)
                C[(size_t)(bm + wm + i * 16 + kq * 4 + r) * N + (bn + wn + j * 16 + fr)] = acc[i][j][r];
}

// ---------------- wval: MFMA 128x128 tile, split-K over blockIdx.y ----------------
// Cpart[kz][NTOK][128] = u[128-tile, kz-quarter] @ Wv[:, kz-quarter]^T
__global__ __launch_bounds__(256) void gemm_wval_splitk(const float* __restrict__ A,
                                                        const float* __restrict__ B,
                                                        float* __restrict__ Cpart) {
    __shared__ __align__(16) unsigned short As[4][128][8];
    __shared__ __align__(16) unsigned short Bs[4][128][8];
    const int t    = threadIdx.x;
    const int lane = t & 63;
    const int w    = t >> 6;
    const int wm   = (w & 1) * 64;
    const int wn   = (w >> 1) * 64;
    const int bm   = blockIdx.x * 128;
    const int kz   = blockIdx.y;
    const int kbeg = kz * 256;

    const int srow = t & 127;
    const int skg  = t >> 7;
    const float* Ap = A + (size_t)(bm + srow) * DMODEL;
    const float* Bp = B + (size_t)srow * DMODEL;

    const int fr = lane & 15;
    const int kq = lane >> 4;

    f32x4 acc[4][4] = {};

    for (int k0 = kbeg; k0 < kbeg + 256; k0 += 32) {
        #pragma unroll
        for (int ii = 0; ii < 2; ++ii) {
            const int kg = skg + ii * 2;
            const float4 a0 = *(const float4*)(Ap + k0 + kg * 8);
            const float4 a1 = *(const float4*)(Ap + k0 + kg * 8 + 4);
            const float4 b0 = *(const float4*)(Bp + k0 + kg * 8);
            const float4 b1 = *(const float4*)(Bp + k0 + kg * 8 + 4);
            unsigned short* da = &As[kg][srow][0];
            da[0] = f2bf_raw(a0.x); da[1] = f2bf_raw(a0.y);
            da[2] = f2bf_raw(a0.z); da[3] = f2bf_raw(a0.w);
            da[4] = f2bf_raw(a1.x); da[5] = f2bf_raw(a1.y);
            da[6] = f2bf_raw(a1.z); da[7] = f2bf_raw(a1.w);
            unsigned short* db = &Bs[kg][srow][0];
            db[0] = f2bf_raw(b0.x); db[1] = f2bf_raw(b0.y);
            db[2] = f2bf_raw(b0.z); db[3] = f2bf_raw(b0.w);
            db[4] = f2bf_raw(b1.x); db[5] = f2bf_raw(b1.y);
            db[6] = f2bf_raw(b1.z); db[7] = f2bf_raw(b1.w);
        }
        __syncthreads();
        bf16x8 af[4], bfv[4];
        #pragma unroll
        for (int i = 0; i < 4; ++i) af[i]  = *(const bf16x8*)&As[kq][wm + i * 16 + fr][0];
        #pragma unroll
        for (int j = 0; j < 4; ++j) bfv[j] = *(const bf16x8*)&Bs[kq][wn + j * 16 + fr][0];
        #pragma unroll
        for (int i = 0; i < 4; ++i)
            #pragma unroll
            for (int j = 0; j < 4; ++j)
                acc[i][j] = __builtin_amdgcn_mfma_f32_16x16x32_bf16(af[i], bfv[j], acc[i][j], 0, 0, 0);
        __syncthreads();
    }
    float* Cp = Cpart + (size_t)kz * NTOK * 128;
    #pragma unroll
    for (int i = 0; i < 4; ++i)
        #pragma unroll
        for (int j = 0; j < 4; ++j)
            #pragma unroll
            for (int r = 0; r < 4; ++r)
                Cp[(size_t)(bm + wm + i * 16 + kq * 4 + r) * 128 + (wn + j * 16 + fr)] = acc[i][j][r];
}

// ---------------- fp32 GEMM 64x128 tile, split-K=8, dbuf, all-2-way LDS ----------
// B rows 0..63 from Wq, rows 64..127 from Wwk. Fused gate partials.
// Cpart[kz][NTOK][128] = u[M-tile, kz-eighth] @ B^T ; gatep[kz][NTOK] = u . Wg partial
__global__ __launch_bounds__(256, 4) void gemm_f32_64(const float* __restrict__ A,
                                                      const float* __restrict__ Wq,
                                                      const float* __restrict__ Wwk,
                                                      const float* __restrict__ Wg,
                                                      float* __restrict__ Cpart,
                                                      float* __restrict__ gatep) {
    __shared__ __align__(16) float As[2][16][68];
    __shared__ __align__(16) float Bs[2][16][140];
    __shared__ float sWg[128];
    const int t    = threadIdx.x;
    const int bm   = blockIdx.x * 64;
    const int kz   = blockIdx.z;
    const int kbeg = kz * 128;         // K slice = 128
    const int NSTEP = 8;               // 8 steps of 16 k

    const int tx   = t & 15;           // output cols tx*8 .. tx*8+7
    const int ty   = t >> 4;           // output rows ty*4 .. ty*4+3
    const int goff = tx * 8 + ((tx >> 2) << 2);   // gap-swizzled col base (2-way)

    const int arow = t >> 2;           // A staging row 0..63
    const int ac   = (t & 3) * 4;      // A staging k-offset
    const int brow = t >> 1;           // B staging row 0..127
    const int bc   = (t & 1) * 8;      // B staging k-offset
    const int bperm = brow + ((brow >> 5) << 2);  // swizzled B col (2-way)

    const float* Apt = A + (size_t)(bm + arow) * DMODEL + kbeg + ac;
    const float* Bpt = (brow < 64 ? Wq + (size_t)brow * DMODEL
                                  : Wwk + (size_t)(brow - 64) * DMODEL) + kbeg + bc;

    // stage Wg slice (128 floats) once
    if (t < 32) *(float4*)&sWg[t * 4] = *(const float4*)(Wg + kbeg + t * 4);

    f32x2 acc2[4][4] = {};
    float gacc = 0.f;

    // prologue: stage step 0 into buf 0
    float4 av = *(const float4*)(Apt);
    float4 b0 = *(const float4*)(Bpt);
    float4 b1 = *(const float4*)(Bpt + 4);
    As[0][ac + 0][arow] = av.x; As[0][ac + 1][arow] = av.y;
    As[0][ac + 2][arow] = av.z; As[0][ac + 3][arow] = av.w;
    Bs[0][bc + 0][bperm] = b0.x; Bs[0][bc + 1][bperm] = b0.y;
    Bs[0][bc + 2][bperm] = b0.z; Bs[0][bc + 3][bperm] = b0.w;
    Bs[0][bc + 4][bperm] = b1.x; Bs[0][bc + 5][bperm] = b1.y;
    Bs[0][bc + 6][bperm] = b1.z; Bs[0][bc + 7][bperm] = b1.w;
    __syncthreads();

    for (int s = 0; s < NSTEP; ++s) {
        const int cur = s & 1;
        if (s + 1 < NSTEP) {           // issue next-step global loads early
            av = *(const float4*)(Apt + (s + 1) * 16);
            b0 = *(const float4*)(Bpt + (s + 1) * 16);
            b1 = *(const float4*)(Bpt + (s + 1) * 16 + 4);
        }
        #pragma unroll
        for (int kk = 0; kk < 16; ++kk) {
            const float4 a4 = *(const float4*)&As[cur][kk][ty * 4];
            const float4 v0 = *(const float4*)&Bs[cur][kk][goff];
            const float4 v1 = *(const float4*)&Bs[cur][kk][goff + 4];
            const float aa[4] = {a4.x, a4.y, a4.z, a4.w};
            const f32x2 bb[4] = {{v0.x, v0.y}, {v0.z, v0.w}, {v1.x, v1.y}, {v1.z, v1.w}};
            #pragma unroll
            for (int i = 0; i < 4; ++i) {
                const f32x2 ai = {aa[i], aa[i]};
                #pragma unroll
                for (int j = 0; j < 4; ++j)
                    acc2[i][j] = __builtin_elementwise_fma(ai, bb[j], acc2[i][j]);
            }
        }
        {   // fused gate partial: thread covers k-subrange ac..ac+3 of row arow
            float ga = 0.f;
            #pragma unroll
            for (int kk = 0; kk < 4; ++kk)
                ga += As[cur][ac + kk][arow] * sWg[s * 16 + ac + kk];
            gacc += ga;
        }
        if (s + 1 < NSTEP) {           // write into the other buffer
            const int nb = cur ^ 1;
            As[nb][ac + 0][arow] = av.x; As[nb][ac + 1][arow] = av.y;
            As[nb][ac + 2][arow] = av.z; As[nb][ac + 3][arow] = av.w;
            Bs[nb][bc + 0][bperm] = b0.x; Bs[nb][bc + 1][bperm] = b0.y;
            Bs[nb][bc + 2][bperm] = b0.z; Bs[nb][bc + 3][bperm] = b0.w;
            Bs[nb][bc + 4][bperm] = b1.x; Bs[nb][bc + 5][bperm] = b1.y;
            Bs[nb][bc + 6][bperm] = b1.z; Bs[nb][bc + 7][bperm] = b1.w;
        }
        __syncthreads();
    }

    // gate partial: sum the 4 k-chunks of each row (lanes t, t^1, t^2, t^3 share arow)
    {
        float g = gacc;
        g += __shfl_xor(g, 1);
        g += __shfl_xor(g, 2);
        if ((t & 3) == 0) gatep[(size_t)kz * NTOK + bm + arow] = g;
    }

    float* Cp = Cpart + (size_t)kz * NTOK * 128;
    #pragma unroll
    for (int i = 0; i < 4; ++i) {
        float4 o0, o1;
        o0.x = acc2[i][0].x; o0.y = acc2[i][0].y; o0.z = acc2[i][1].x; o0.w = acc2[i][1].y;
        o1.x = acc2[i][2].x; o1.y = acc2[i][2].y; o1.z = acc2[i][3].x; o1.w = acc2[i][3].y;
        float* dst = Cp + (size_t)(bm + ty * 4 + i) * 128 + tx * 8;
        *(float4*)dst       = o0;
        *(float4*)(dst + 4) = o1;
    }
}

// ---------------- deterministic split-K reduces ----------------
__global__ __launch_bounds__(256) void reduce4_kernel(const float* __restrict__ p,
                                                      float* __restrict__ out,
                                                      int n4, int stride4) {
    const int i = (blockIdx.x * 256 + threadIdx.x);
    if (i < n4) {
        const float4 a = ((const float4*)p)[i];
        const float4 b = ((const float4*)p)[i + stride4];
        const float4 c = ((const float4*)p)[i + 2 * stride4];
        const float4 d = ((const float4*)p)[i + 3 * stride4];
        float4 r;
        r.x = (a.x + b.x) + (c.x + d.x);
        r.y = (a.y + b.y) + (c.y + d.y);
        r.z = (a.z + b.z) + (c.z + d.z);
        r.w = (a.w + b.w) + (c.w + d.w);
        ((float4*)out)[i] = r;
    }
}

__global__ __launch_bounds__(256) void reduce8_kernel(const float* __restrict__ p,
                                                      float* __restrict__ out,
                                                      int n4, int stride4) {
    const int i = (blockIdx.x * 256 + threadIdx.x);
    if (i < n4) {
        float4 r;
        const float4 a0 = ((const float4*)p)[i];
        const float4 a1 = ((const float4*)p)[i + stride4];
        const float4 a2 = ((const float4*)p)[i + 2 * stride4];
        const float4 a3 = ((const float4*)p)[i + 3 * stride4];
        const float4 a4 = ((const float4*)p)[i + 4 * stride4];
        const float4 a5 = ((const float4*)p)[i + 5 * stride4];
        const float4 a6 = ((const float4*)p)[i + 6 * stride4];
        const float4 a7 = ((const float4*)p)[i + 7 * stride4];
        r.x = ((a0.x + a1.x) + (a2.x + a3.x)) + ((a4.x + a5.x) + (a6.x + a7.x));
        r.y = ((a0.y + a1.y) + (a2.y + a3.y)) + ((a4.y + a5.y) + (a6.y + a7.y));
        r.z = ((a0.z + a1.z) + (a2.z + a3.z)) + ((a4.z + a5.z) + (a6.z + a7.z));
        r.w = ((a0.w + a1.w) + (a2.w + a3.w)) + ((a4.w + a5.w) + (a6.w + a7.w));
        ((float4*)out)[i] = r;
    }
}

// ---------------- fused routing / gather / score / read / scatter ----------------
__global__ __launch_bounds__(256) void route_kernel(
    const float* __restrict__ memK, const float* __restrict__ memV,
    const float* __restrict__ memT, const float* __restrict__ R,
    const float* __restrict__ Wvsa,
    const float* __restrict__ qw, const float* __restrict__ wvalg,
    const float* __restrict__ gatep, const float* __restrict__ bg,
    float* __restrict__ accK, float* __restrict__ accV, float* __restrict__ accT,
    float* __restrict__ readw) {
    __shared__ float sQK[4][64], sWK[4][64], sQT[4][32], sWT[4][32];
    __shared__ float sSc[4][16], sSim[4][16], sTsim[4][16], sW[4][16];
    __shared__ int   sIdx[4][4], sAst[4][4];
    __shared__ float sEff[4][4];

    const int wv = threadIdx.x >> 6;
    const int lane = threadIdx.x & 63;
    const int n = blockIdx.x * 4 + wv;

    const float qk = qw[(size_t)n * 128 + lane];
    const float wk = qw[(size_t)n * 128 + 64 + lane];
    sQK[wv][lane] = qk;
    sWK[wv][lane] = wk;
    float wk2 = wk * wk;
    #pragma unroll
    for (int off = 1; off < 64; off <<= 1) wk2 += __shfl_xor(wk2, off);
    const float wknorm = sqrtf(wk2) + EPSV;
    __syncthreads();

    {
        const int tg = lane & 31;
        const float* keyp = (lane < 32) ? sQK[wv] : sWK[wv];
        float tacc = 0.f;
        for (int d = 0; d < 64; ++d) tacc += keyp[d] * Wvsa[d * DTAG + tg];
        const float tagv = tanhf(tacc);
        if (lane < 32) sQT[wv][tg] = tagv; else sWT[wv][tg] = tagv;
        float wt2 = (lane >= 32) ? tagv * tagv : 0.f;
        #pragma unroll
        for (int off = 1; off < 64; off <<= 1) wt2 += __shfl_xor(wt2, off);
        const float wtnorm = sqrtf(wt2) + EPSV;

        bool bit = false;
        if (lane < 48) {
            const int h = lane / 12, k = lane % 12;
            float bacc = 0.f;
            for (int d = 0; d < 64; ++d)
                bacc += sQK[wv][d] * R[(size_t)(h * DKEY + d) * NBITS + k];
            bit = bacc > 0.f;
        }
        const unsigned long long mask = __ballot(bit);
        if (lane < 4) sIdx[wv][lane] = (int)((mask >> (12 * lane)) & 0xFFFull);
        __syncthreads();

        const int slot = lane >> 2, sub = lane & 3;
        const int sh = slot >> 2, sa = slot & 3;
        const int rowS = (sh * NBUCKET + sIdx[wv][sh]) * ASSOC + sa;
        const float* Kp = memK + (size_t)rowS * DKEY;
        const float* Tp = memT + (size_t)rowS * DTAG;
        float d_qk = 0, d_wk = 0, d_kk = 0, d_qt = 0, d_wt = 0, d_tt = 0;
        for (int j = 0; j < 16; ++j) {
            const int d = sub * 16 + j;
            const float kv = Kp[d];
            d_qk += sQK[wv][d] * kv;
            d_wk += sWK[wv][d] * kv;
            d_kk += kv * kv;
        }
        for (int j = 0; j < 8; ++j) {
            const int d = sub * 8 + j;
            const float tv = Tp[d];
            d_qt += sQT[wv][d] * tv;
            d_wt += sWT[wv][d] * tv;
            d_tt += tv * tv;
        }
        #pragma unroll
        for (int off = 1; off <= 2; off <<= 1) {
            d_qk += __shfl_xor(d_qk, off);
            d_wk += __shfl_xor(d_wk, off);
            d_kk += __shfl_xor(d_kk, off);
            d_qt += __shfl_xor(d_qt, off);
            d_wt += __shfl_xor(d_wt, off);
            d_tt += __shfl_xor(d_tt, off);
        }
        if (sub == 0) {
            sSc[wv][slot]   = d_qk * 0.125f + d_qt * 0.17677669529663687f;
            sSim[wv][slot]  = d_wk / (wknorm * (sqrtf(d_kk) + EPSV));
            sTsim[wv][slot] = d_wt / (wtnorm * (sqrtf(d_tt) + EPSV));
        }
    }
    __syncthreads();

    if (lane < 16) {
        const float sc = sSc[wv][lane];
        float m = sc;
        #pragma unroll
        for (int off = 1; off < 16; off <<= 1) m = fmaxf(m, __shfl_xor(m, off, 16));
        const float e = expf(sc - m);
        float ssum = e;
        #pragma unroll
        for (int off = 1; off < 16; off <<= 1) ssum += __shfl_xor(ssum, off, 16);
        sW[wv][lane] = e / ssum;
    }
    // gate = sigmoid(sum of 8 split-K partials + bg)
    float gl = bg[0];
    #pragma unroll
    for (int z = 0; z < 8; ++z) gl += gatep[(size_t)z * NTOK + n];
    const float gate = 1.f / (1.f + expf(-gl));
    if (lane < 4) {
        float bs = -1e30f; int as = 0; float mt = -1e30f;
        #pragma unroll
        for (int aa = 0; aa < 4; ++aa) {
            const float sv = sSim[wv][lane * 4 + aa];
            if (sv > bs) { bs = sv; as = aa; }
            mt = fmaxf(mt, sTsim[wv][lane * 4 + aa]);
        }
        const float novelty = 1.f - mt;
        float e = 0.1f * gate;
        if (!(gate > 0.5f) || !(bs >= 0.f) || !(novelty >= 0.f)) e = 0.f;
        sEff[wv][lane] = e;
        sAst[wv][lane] = as;
    }
    __syncthreads();

    float r0 = 0.f, r1 = 0.f;
    #pragma unroll
    for (int s2 = 0; s2 < 16; ++s2) {
        const int hh = s2 >> 2, aa = s2 & 3;
        const int rw = (hh * NBUCKET + sIdx[wv][hh]) * ASSOC + aa;
        const float wgt = sW[wv][s2];
        const float* Vp = memV + (size_t)rw * DVAL;
        r0 += wgt * Vp[lane];
        r1 += wgt * Vp[64 + lane];
    }
    readw[(size_t)n * DVAL + lane]      = r0;
    readw[(size_t)n * DVAL + 64 + lane] = r1;

    const float wv0 = wvalg[(size_t)n * DVAL + lane];
    const float wv1 = wvalg[(size_t)n * DVAL + 64 + lane];
    for (int hh = 0; hh < 4; ++hh) {
        const float e = sEff[wv][hh];
        if (e == 0.f) continue;
        const int rw = (hh * NBUCKET + sIdx[wv][hh]) * ASSOC + sAst[wv][hh];
        atomicAdd(&accK[(size_t)rw * DKEY + lane],
                  e * (sWK[wv][lane] - memK[(size_t)rw * DKEY + lane]));
        atomicAdd(&accV[(size_t)rw * DVAL + lane],
                  e * (wv0 - memV[(size_t)rw * DVAL + lane]));
        atomicAdd(&accV[(size_t)rw * DVAL + 64 + lane],
                  e * (wv1 - memV[(size_t)rw * DVAL + 64 + lane]));
        if (lane < 32)
            atomicAdd(&accT[(size_t)rw * DTAG + lane],
                      e * (sWT[wv][lane] - memT[(size_t)rw * DTAG + lane]));
    }
}

// ---------------- launcher ----------------
extern "C" void kernel_launch(void* const* d_in, const int* in_sizes, int n_in,
                              void* d_out, int out_size, void* d_ws, size_t ws_size,
                              hipStream_t stream) {
    const float* u    = (const float*)d_in[0];
    const float* memK = (const float*)d_in[1];
    const float* memV = (const float*)d_in[2];
    const float* memT = (const float*)d_in[3];
    const float* Wq   = (const float*)d_in[4];
    const float* Wwk  = (const float*)d_in[5];
    const float* Wv   = (const float*)d_in[6];
    const float* Wo   = (const float*)d_in[7];
    const float* Wg   = (const float*)d_in[8];
    const float* bg   = (const float*)d_in[9];
    const float* Wvsa = (const float*)d_in[10];
    const float* R    = (const float*)d_in[11];

    const int nK = HN * NBUCKET * ASSOC * DKEY;   // 4,194,304
    const int nV = HN * NBUCKET * ASSOC * DVAL;   // 8,388,608
    const int nT = HN * NBUCKET * ASSOC * DTAG;   // 2,097,152

    float* y_out = (float*)d_out;
    float* K_out = y_out + (size_t)NTOK * DMODEL;
    float* V_out = K_out + nK;
    float* T_out = V_out + nV;

    float* qw    = (float*)d_ws;                       // [NTOK][128] qkey|wkey
    float* wvalg = qw    + (size_t)NTOK * 128;         // [NTOK][128]
    float* readw = wvalg + (size_t)NTOK * 128;         // [NTOK][128]
    float* gatep = readw + (size_t)NTOK * 128;         // [8][NTOK] gate partials
    // ws usage ~ 25.7 MB

    // split-K partials live in d_out's y region (overwritten later by y-GEMM):
    //   qw partials: [8][NTOK][128] floats = 67.1 MB = exactly the y region
    //   wval partials: [4][NTOK][128] = 33.5 MB, reuses the same region after reduce8
    float* part = y_out;

    // 1) qkey|wkey projection (fp32, 64x128 tile, split-K=8, fused gate partials)
    gemm_f32_64<<<dim3(NTOK / 64, 1, 8), 256, 0, stream>>>(u, Wq, Wwk, Wg, part, gatep);
    reduce8_kernel<<<(NTOK * 128 / 4 + 255) / 256, 256, 0, stream>>>(part, qw, NTOK * 128 / 4, NTOK * 128 / 4);

    // 2) wval projection (bf16 MFMA, split-K=4, partials reuse y region)
    gemm_wval_splitk<<<dim3(NTOK / 128, 4), 256, 0, stream>>>(u, Wv, part);
    reduce4_kernel<<<(NTOK * 128 / 4 + 255) / 256, 256, 0, stream>>>(part, wvalg, NTOK * 128 / 4, NTOK * 128 / 4);

    // 3) seed outputs with pristine memories
    hipMemcpyAsync(K_out, memK, (size_t)nK * 4, hipMemcpyDeviceToDevice, stream);
    hipMemcpyAsync(V_out, memV, (size_t)nV * 4, hipMemcpyDeviceToDevice, stream);
    hipMemcpyAsync(T_out, memT, (size_t)nT * 4, hipMemcpyDeviceToDevice, stream);

    // 4) fused routing / gather / score / read / scatter (atomics into d_out)
    route_kernel<<<NTOK / 4, 256, 0, stream>>>(memK, memV, memT, R, Wvsa,
                                               qw, wvalg, gatep, bg,
                                               K_out, V_out, T_out, readw);

    // 5) y = read @ Wo^T (bf16 MFMA)
    gemm_mfma<<<dim3(NTOK / 128, DMODEL / 128), 256, 0, stream>>>(readw, Wo, y_out, NTOK, DMODEL, DVAL);
}

// Round 5
// 449.405 us; speedup vs baseline: 1.0972x; 1.0972x over previous
//
#include <hip/hip_runtime.h>
#include <hip/hip_bf16.h>
#include <math.h>

#define NTOK    16384
#define DMODEL  1024
#define HN      4
#define NBUCKET 4096
#define ASSOC   4
#define DKEY    64
#define DVAL    128
#define DTAG    32
#define NBITS   12
#define EPSV    1e-6f

typedef __bf16 bf16x8 __attribute__((ext_vector_type(8)));
typedef float  f32x4  __attribute__((ext_vector_type(4)));
typedef float  f32x2  __attribute__((ext_vector_type(2)));

__device__ __forceinline__ unsigned short f2bf_raw(float f) {
    __hip_bfloat16 h = __float2bfloat16(f);
    return *(unsigned short*)&h;
}

// ---------------- MFMA GEMM 128x128 tile: C[M,N] = A[M,K] @ B[N,K]^T ----------------
__global__ __launch_bounds__(256) void gemm_mfma(const float* __restrict__ A,
                                                 const float* __restrict__ B,
                                                 float* __restrict__ C,
                                                 int M, int N, int K) {
    __shared__ __align__(16) unsigned short As[4][128][8];
    __shared__ __align__(16) unsigned short Bs[4][128][8];
    const int t    = threadIdx.x;
    const int lane = t & 63;
    const int w    = t >> 6;
    const int wm   = (w & 1) * 64;
    const int wn   = (w >> 1) * 64;
    const int bm   = blockIdx.x * 128;
    const int bn   = blockIdx.y * 128;

    const int srow = t & 127;
    const int skg  = t >> 7;
    const float* Ap = A + (size_t)(bm + srow) * K;
    const float* Bp = B + (size_t)(bn + srow) * K;

    const int fr = lane & 15;
    const int kq = lane >> 4;

    f32x4 acc[4][4] = {};

    for (int k0 = 0; k0 < K; k0 += 32) {
        #pragma unroll
        for (int ii = 0; ii < 2; ++ii) {
            const int kg = skg + ii * 2;
            const float4 a0 = *(const float4*)(Ap + k0 + kg * 8);
            const float4 a1 = *(const float4*)(Ap + k0 + kg * 8 + 4);
            const float4 b0 = *(const float4*)(Bp + k0 + kg * 8);
            const float4 b1 = *(const float4*)(Bp + k0 + kg * 8 + 4);
            unsigned short* da = &As[kg][srow][0];
            da[0] = f2bf_raw(a0.x); da[1] = f2bf_raw(a0.y);
            da[2] = f2bf_raw(a0.z); da[3] = f2bf_raw(a0.w);
            da[4] = f2bf_raw(a1.x); da[5] = f2bf_raw(a1.y);
            da[6] = f2bf_raw(a1.z); da[7] = f2bf_raw(a1.w);
            unsigned short* db = &Bs[kg][srow][0];
            db[0] = f2bf_raw(b0.x); db[1] = f2bf_raw(b0.y);
            db[2] = f2bf_raw(b0.z); db[3] = f2bf_raw(b0.w);
            db[4] = f2bf_raw(b1.x); db[5] = f2bf_raw(b1.y);
            db[6] = f2bf_raw(b1.z); db[7] = f2bf_raw(b1.w);
        }
        __syncthreads();
        bf16x8 af[4], bfv[4];
        #pragma unroll
        for (int i = 0; i < 4; ++i) af[i]  = *(const bf16x8*)&As[kq][wm + i * 16 + fr][0];
        #pragma unroll
        for (int j = 0; j < 4; ++j) bfv[j] = *(const bf16x8*)&Bs[kq][wn + j * 16 + fr][0];
        #pragma unroll
        for (int i = 0; i < 4; ++i)
            #pragma unroll
            for (int j = 0; j < 4; ++j)
                acc[i][j] = __builtin_amdgcn_mfma_f32_16x16x32_bf16(af[i], bfv[j], acc[i][j], 0, 0, 0);
        __syncthreads();
    }
    #pragma unroll
    for (int i = 0; i < 4; ++i)
        #pragma unroll
        for (int j = 0; j < 4; ++j)
            #pragma unroll
            for (int r = 0; r < 4; ++r)
                C[(size_t)(bm + wm + i * 16 + kq * 4 + r) * N + (bn + wn + j * 16 + fr)] = acc[i][j][r];
}

// ---------------- wval: MFMA 128x128 tile, split-K over blockIdx.y ----------------
// Cpart[kz][NTOK][128] = u[128-tile, kz-quarter] @ Wv[:, kz-quarter]^T
__global__ __launch_bounds__(256) void gemm_wval_splitk(const float* __restrict__ A,
                                                        const float* __restrict__ B,
                                                        float* __restrict__ Cpart) {
    __shared__ __align__(16) unsigned short As[4][128][8];
    __shared__ __align__(16) unsigned short Bs[4][128][8];
    const int t    = threadIdx.x;
    const int lane = t & 63;
    const int w    = t >> 6;
    const int wm   = (w & 1) * 64;
    const int wn   = (w >> 1) * 64;
    const int bm   = blockIdx.x * 128;
    const int kz   = blockIdx.y;
    const int kbeg = kz * 256;

    const int srow = t & 127;
    const int skg  = t >> 7;
    const float* Ap = A + (size_t)(bm + srow) * DMODEL;
    const float* Bp = B + (size_t)srow * DMODEL;

    const int fr = lane & 15;
    const int kq = lane >> 4;

    f32x4 acc[4][4] = {};

    for (int k0 = kbeg; k0 < kbeg + 256; k0 += 32) {
        #pragma unroll
        for (int ii = 0; ii < 2; ++ii) {
            const int kg = skg + ii * 2;
            const float4 a0 = *(const float4*)(Ap + k0 + kg * 8);
            const float4 a1 = *(const float4*)(Ap + k0 + kg * 8 + 4);
            const float4 b0 = *(const float4*)(Bp + k0 + kg * 8);
            const float4 b1 = *(const float4*)(Bp + k0 + kg * 8 + 4);
            unsigned short* da = &As[kg][srow][0];
            da[0] = f2bf_raw(a0.x); da[1] = f2bf_raw(a0.y);
            da[2] = f2bf_raw(a0.z); da[3] = f2bf_raw(a0.w);
            da[4] = f2bf_raw(a1.x); da[5] = f2bf_raw(a1.y);
            da[6] = f2bf_raw(a1.z); da[7] = f2bf_raw(a1.w);
            unsigned short* db = &Bs[kg][srow][0];
            db[0] = f2bf_raw(b0.x); db[1] = f2bf_raw(b0.y);
            db[2] = f2bf_raw(b0.z); db[3] = f2bf_raw(b0.w);
            db[4] = f2bf_raw(b1.x); db[5] = f2bf_raw(b1.y);
            db[6] = f2bf_raw(b1.z); db[7] = f2bf_raw(b1.w);
        }
        __syncthreads();
        bf16x8 af[4], bfv[4];
        #pragma unroll
        for (int i = 0; i < 4; ++i) af[i]  = *(const bf16x8*)&As[kq][wm + i * 16 + fr][0];
        #pragma unroll
        for (int j = 0; j < 4; ++j) bfv[j] = *(const bf16x8*)&Bs[kq][wn + j * 16 + fr][0];
        #pragma unroll
        for (int i = 0; i < 4; ++i)
            #pragma unroll
            for (int j = 0; j < 4; ++j)
                acc[i][j] = __builtin_amdgcn_mfma_f32_16x16x32_bf16(af[i], bfv[j], acc[i][j], 0, 0, 0);
        __syncthreads();
    }
    float* Cp = Cpart + (size_t)kz * NTOK * 128;
    #pragma unroll
    for (int i = 0; i < 4; ++i)
        #pragma unroll
        for (int j = 0; j < 4; ++j)
            #pragma unroll
            for (int r = 0; r < 4; ++r)
                Cp[(size_t)(bm + wm + i * 16 + kq * 4 + r) * 128 + (wn + j * 16 + fr)] = acc[i][j][r];
}

// ---------------- fp32 GEMM 64x128 tile, split-K=8, dbuf ----------
// B rows 0..63 from Wq, rows 64..127 from Wwk. Fused gate partials.
// NOTE: plain __launch_bounds__(256). The (256,4) variant forced VGPR=64 on the
// unified gfx950 RF -> scratch spills -> 460 MB HBM traffic (round-4 counters).
__global__ __launch_bounds__(256) void gemm_f32_64(const float* __restrict__ A,
                                                   const float* __restrict__ Wq,
                                                   const float* __restrict__ Wwk,
                                                   const float* __restrict__ Wg,
                                                   float* __restrict__ Cpart,
                                                   float* __restrict__ gatep) {
    __shared__ __align__(16) float As[2][16][68];
    __shared__ __align__(16) float Bs[2][16][140];
    __shared__ float sWg[128];
    const int t    = threadIdx.x;
    const int bm   = blockIdx.x * 64;
    const int kz   = blockIdx.z;
    const int kbeg = kz * 128;         // K slice = 128
    const int NSTEP = 8;               // 8 steps of 16 k

    const int tx   = t & 15;           // output cols tx*8 .. tx*8+7
    const int ty   = t >> 4;           // output rows ty*4 .. ty*4+3
    const int goff = tx * 8 + ((tx >> 2) << 2);   // gap-swizzled col base

    const int arow = t >> 2;           // A staging row 0..63
    const int ac   = (t & 3) * 4;      // A staging k-offset
    const int brow = t >> 1;           // B staging row 0..127
    const int bc   = (t & 1) * 8;      // B staging k-offset
    const int bperm = brow + ((brow >> 5) << 2);  // swizzled B col

    const float* Apt = A + (size_t)(bm + arow) * DMODEL + kbeg + ac;
    const float* Bpt = (brow < 64 ? Wq + (size_t)brow * DMODEL
                                  : Wwk + (size_t)(brow - 64) * DMODEL) + kbeg + bc;

    // stage Wg slice (128 floats) once
    if (t < 32) *(float4*)&sWg[t * 4] = *(const float4*)(Wg + kbeg + t * 4);

    f32x2 acc2[4][4] = {};
    float gacc = 0.f;

    // prologue: stage step 0 into buf 0
    float4 av = *(const float4*)(Apt);
    float4 b0 = *(const float4*)(Bpt);
    float4 b1 = *(const float4*)(Bpt + 4);
    As[0][ac + 0][arow] = av.x; As[0][ac + 1][arow] = av.y;
    As[0][ac + 2][arow] = av.z; As[0][ac + 3][arow] = av.w;
    Bs[0][bc + 0][bperm] = b0.x; Bs[0][bc + 1][bperm] = b0.y;
    Bs[0][bc + 2][bperm] = b0.z; Bs[0][bc + 3][bperm] = b0.w;
    Bs[0][bc + 4][bperm] = b1.x; Bs[0][bc + 5][bperm] = b1.y;
    Bs[0][bc + 6][bperm] = b1.z; Bs[0][bc + 7][bperm] = b1.w;
    __syncthreads();

    for (int s = 0; s < NSTEP; ++s) {
        const int cur = s & 1;
        if (s + 1 < NSTEP) {           // issue next-step global loads early
            av = *(const float4*)(Apt + (s + 1) * 16);
            b0 = *(const float4*)(Bpt + (s + 1) * 16);
            b1 = *(const float4*)(Bpt + (s + 1) * 16 + 4);
        }
        #pragma unroll
        for (int kk = 0; kk < 16; ++kk) {
            const float4 a4 = *(const float4*)&As[cur][kk][ty * 4];
            const float4 v0 = *(const float4*)&Bs[cur][kk][goff];
            const float4 v1 = *(const float4*)&Bs[cur][kk][goff + 4];
            const float aa[4] = {a4.x, a4.y, a4.z, a4.w};
            const f32x2 bb[4] = {{v0.x, v0.y}, {v0.z, v0.w}, {v1.x, v1.y}, {v1.z, v1.w}};
            #pragma unroll
            for (int i = 0; i < 4; ++i) {
                const f32x2 ai = {aa[i], aa[i]};
                #pragma unroll
                for (int j = 0; j < 4; ++j)
                    acc2[i][j] = __builtin_elementwise_fma(ai, bb[j], acc2[i][j]);
            }
        }
        {   // fused gate partial: thread covers k-subrange ac..ac+3 of row arow
            float ga = 0.f;
            #pragma unroll
            for (int kk = 0; kk < 4; ++kk)
                ga += As[cur][ac + kk][arow] * sWg[s * 16 + ac + kk];
            gacc += ga;
        }
        if (s + 1 < NSTEP) {           // write into the other buffer
            const int nb = cur ^ 1;
            As[nb][ac + 0][arow] = av.x; As[nb][ac + 1][arow] = av.y;
            As[nb][ac + 2][arow] = av.z; As[nb][ac + 3][arow] = av.w;
            Bs[nb][bc + 0][bperm] = b0.x; Bs[nb][bc + 1][bperm] = b0.y;
            Bs[nb][bc + 2][bperm] = b0.z; Bs[nb][bc + 3][bperm] = b0.w;
            Bs[nb][bc + 4][bperm] = b1.x; Bs[nb][bc + 5][bperm] = b1.y;
            Bs[nb][bc + 6][bperm] = b1.z; Bs[nb][bc + 7][bperm] = b1.w;
        }
        __syncthreads();
    }

    // gate partial: sum the 4 k-chunks of each row (lanes t, t^1, t^2, t^3 share arow)
    {
        float g = gacc;
        g += __shfl_xor(g, 1);
        g += __shfl_xor(g, 2);
        if ((t & 3) == 0) gatep[(size_t)kz * NTOK + bm + arow] = g;
    }

    float* Cp = Cpart + (size_t)kz * NTOK * 128;
    #pragma unroll
    for (int i = 0; i < 4; ++i) {
        float4 o0, o1;
        o0.x = acc2[i][0].x; o0.y = acc2[i][0].y; o0.z = acc2[i][1].x; o0.w = acc2[i][1].y;
        o1.x = acc2[i][2].x; o1.y = acc2[i][2].y; o1.z = acc2[i][3].x; o1.w = acc2[i][3].y;
        float* dst = Cp + (size_t)(bm + ty * 4 + i) * 128 + tx * 8;
        *(float4*)dst       = o0;
        *(float4*)(dst + 4) = o1;
    }
}

// ---------------- deterministic split-K reduces ----------------
__global__ __launch_bounds__(256) void reduce4_kernel(const float* __restrict__ p,
                                                      float* __restrict__ out,
                                                      int n4, int stride4) {
    const int i = (blockIdx.x * 256 + threadIdx.x);
    if (i < n4) {
        const float4 a = ((const float4*)p)[i];
        const float4 b = ((const float4*)p)[i + stride4];
        const float4 c = ((const float4*)p)[i + 2 * stride4];
        const float4 d = ((const float4*)p)[i + 3 * stride4];
        float4 r;
        r.x = (a.x + b.x) + (c.x + d.x);
        r.y = (a.y + b.y) + (c.y + d.y);
        r.z = (a.z + b.z) + (c.z + d.z);
        r.w = (a.w + b.w) + (c.w + d.w);
        ((float4*)out)[i] = r;
    }
}

__global__ __launch_bounds__(256) void reduce8_kernel(const float* __restrict__ p,
                                                      float* __restrict__ out,
                                                      int n4, int stride4) {
    const int i = (blockIdx.x * 256 + threadIdx.x);
    if (i < n4) {
        float4 r;
        const float4 a0 = ((const float4*)p)[i];
        const float4 a1 = ((const float4*)p)[i + stride4];
        const float4 a2 = ((const float4*)p)[i + 2 * stride4];
        const float4 a3 = ((const float4*)p)[i + 3 * stride4];
        const float4 a4 = ((const float4*)p)[i + 4 * stride4];
        const float4 a5 = ((const float4*)p)[i + 5 * stride4];
        const float4 a6 = ((const float4*)p)[i + 6 * stride4];
        const float4 a7 = ((const float4*)p)[i + 7 * stride4];
        r.x = ((a0.x + a1.x) + (a2.x + a3.x)) + ((a4.x + a5.x) + (a6.x + a7.x));
        r.y = ((a0.y + a1.y) + (a2.y + a3.y)) + ((a4.y + a5.y) + (a6.y + a7.y));
        r.z = ((a0.z + a1.z) + (a2.z + a3.z)) + ((a4.z + a5.z) + (a6.z + a7.z));
        r.w = ((a0.w + a1.w) + (a2.w + a3.w)) + ((a4.w + a5.w) + (a6.w + a7.w));
        ((float4*)out)[i] = r;
    }
}

// ---------------- fused routing / gather / score / read / scatter ----------------
__global__ __launch_bounds__(256) void route_kernel(
    const float* __restrict__ memK, const float* __restrict__ memV,
    const float* __restrict__ memT, const float* __restrict__ R,
    const float* __restrict__ Wvsa,
    const float* __restrict__ qw, const float* __restrict__ wvalg,
    const float* __restrict__ gatep, const float* __restrict__ bg,
    float* __restrict__ accK, float* __restrict__ accV, float* __restrict__ accT,
    float* __restrict__ readw) {
    __shared__ float sQK[4][64], sWK[4][64], sQT[4][32], sWT[4][32];
    __shared__ float sSc[4][16], sSim[4][16], sTsim[4][16], sW[4][16];
    __shared__ int   sIdx[4][4], sAst[4][4];
    __shared__ float sEff[4][4];

    const int wv = threadIdx.x >> 6;
    const int lane = threadIdx.x & 63;
    const int n = blockIdx.x * 4 + wv;

    const float qk = qw[(size_t)n * 128 + lane];
    const float wk = qw[(size_t)n * 128 + 64 + lane];
    sQK[wv][lane] = qk;
    sWK[wv][lane] = wk;
    float wk2 = wk * wk;
    #pragma unroll
    for (int off = 1; off < 64; off <<= 1) wk2 += __shfl_xor(wk2, off);
    const float wknorm = sqrtf(wk2) + EPSV;
    __syncthreads();

    {
        const int tg = lane & 31;
        const float* keyp = (lane < 32) ? sQK[wv] : sWK[wv];
        float tacc = 0.f;
        for (int d = 0; d < 64; ++d) tacc += keyp[d] * Wvsa[d * DTAG + tg];
        const float tagv = tanhf(tacc);
        if (lane < 32) sQT[wv][tg] = tagv; else sWT[wv][tg] = tagv;
        float wt2 = (lane >= 32) ? tagv * tagv : 0.f;
        #pragma unroll
        for (int off = 1; off < 64; off <<= 1) wt2 += __shfl_xor(wt2, off);
        const float wtnorm = sqrtf(wt2) + EPSV;

        bool bit = false;
        if (lane < 48) {
            const int h = lane / 12, k = lane % 12;
            float bacc = 0.f;
            for (int d = 0; d < 64; ++d)
                bacc += sQK[wv][d] * R[(size_t)(h * DKEY + d) * NBITS + k];
            bit = bacc > 0.f;
        }
        const unsigned long long mask = __ballot(bit);
        if (lane < 4) sIdx[wv][lane] = (int)((mask >> (12 * lane)) & 0xFFFull);
        __syncthreads();

        const int slot = lane >> 2, sub = lane & 3;
        const int sh = slot >> 2, sa = slot & 3;
        const int rowS = (sh * NBUCKET + sIdx[wv][sh]) * ASSOC + sa;
        const float* Kp = memK + (size_t)rowS * DKEY;
        const float* Tp = memT + (size_t)rowS * DTAG;
        float d_qk = 0, d_wk = 0, d_kk = 0, d_qt = 0, d_wt = 0, d_tt = 0;
        for (int j = 0; j < 16; ++j) {
            const int d = sub * 16 + j;
            const float kv = Kp[d];
            d_qk += sQK[wv][d] * kv;
            d_wk += sWK[wv][d] * kv;
            d_kk += kv * kv;
        }
        for (int j = 0; j < 8; ++j) {
            const int d = sub * 8 + j;
            const float tv = Tp[d];
            d_qt += sQT[wv][d] * tv;
            d_wt += sWT[wv][d] * tv;
            d_tt += tv * tv;
        }
        #pragma unroll
        for (int off = 1; off <= 2; off <<= 1) {
            d_qk += __shfl_xor(d_qk, off);
            d_wk += __shfl_xor(d_wk, off);
            d_kk += __shfl_xor(d_kk, off);
            d_qt += __shfl_xor(d_qt, off);
            d_wt += __shfl_xor(d_wt, off);
            d_tt += __shfl_xor(d_tt, off);
        }
        if (sub == 0) {
            sSc[wv][slot]   = d_qk * 0.125f + d_qt * 0.17677669529663687f;
            sSim[wv][slot]  = d_wk / (wknorm * (sqrtf(d_kk) + EPSV));
            sTsim[wv][slot] = d_wt / (wtnorm * (sqrtf(d_tt) + EPSV));
        }
    }
    __syncthreads();

    if (lane < 16) {
        const float sc = sSc[wv][lane];
        float m = sc;
        #pragma unroll
        for (int off = 1; off < 16; off <<= 1) m = fmaxf(m, __shfl_xor(m, off, 16));
        const float e = expf(sc - m);
        float ssum = e;
        #pragma unroll
        for (int off = 1; off < 16; off <<= 1) ssum += __shfl_xor(ssum, off, 16);
        sW[wv][lane] = e / ssum;
    }
    // gate = sigmoid(sum of 8 split-K partials + bg)
    float gl = bg[0];
    #pragma unroll
    for (int z = 0; z < 8; ++z) gl += gatep[(size_t)z * NTOK + n];
    const float gate = 1.f / (1.f + expf(-gl));
    if (lane < 4) {
        float bs = -1e30f; int as = 0; float mt = -1e30f;
        #pragma unroll
        for (int aa = 0; aa < 4; ++aa) {
            const float sv = sSim[wv][lane * 4 + aa];
            if (sv > bs) { bs = sv; as = aa; }
            mt = fmaxf(mt, sTsim[wv][lane * 4 + aa]);
        }
        const float novelty = 1.f - mt;
        float e = 0.1f * gate;
        if (!(gate > 0.5f) || !(bs >= 0.f) || !(novelty >= 0.f)) e = 0.f;
        sEff[wv][lane] = e;
        sAst[wv][lane] = as;
    }
    __syncthreads();

    float r0 = 0.f, r1 = 0.f;
    #pragma unroll
    for (int s2 = 0; s2 < 16; ++s2) {
        const int hh = s2 >> 2, aa = s2 & 3;
        const int rw = (hh * NBUCKET + sIdx[wv][hh]) * ASSOC + aa;
        const float wgt = sW[wv][s2];
        const float* Vp = memV + (size_t)rw * DVAL;
        r0 += wgt * Vp[lane];
        r1 += wgt * Vp[64 + lane];
    }
    readw[(size_t)n * DVAL + lane]      = r0;
    readw[(size_t)n * DVAL + 64 + lane] = r1;

    const float wv0 = wvalg[(size_t)n * DVAL + lane];
    const float wv1 = wvalg[(size_t)n * DVAL + 64 + lane];
    for (int hh = 0; hh < 4; ++hh) {
        const float e = sEff[wv][hh];
        if (e == 0.f) continue;
        const int rw = (hh * NBUCKET + sIdx[wv][hh]) * ASSOC + sAst[wv][hh];
        atomicAdd(&accK[(size_t)rw * DKEY + lane],
                  e * (sWK[wv][lane] - memK[(size_t)rw * DKEY + lane]));
        atomicAdd(&accV[(size_t)rw * DVAL + lane],
                  e * (wv0 - memV[(size_t)rw * DVAL + lane]));
        atomicAdd(&accV[(size_t)rw * DVAL + 64 + lane],
                  e * (wv1 - memV[(size_t)rw * DVAL + 64 + lane]));
        if (lane < 32)
            atomicAdd(&accT[(size_t)rw * DTAG + lane],
                      e * (sWT[wv][lane] - memT[(size_t)rw * DTAG + lane]));
    }
}

// ---------------- launcher ----------------
extern "C" void kernel_launch(void* const* d_in, const int* in_sizes, int n_in,
                              void* d_out, int out_size, void* d_ws, size_t ws_size,
                              hipStream_t stream) {
    const float* u    = (const float*)d_in[0];
    const float* memK = (const float*)d_in[1];
    const float* memV = (const float*)d_in[2];
    const float* memT = (const float*)d_in[3];
    const float* Wq   = (const float*)d_in[4];
    const float* Wwk  = (const float*)d_in[5];
    const float* Wv   = (const float*)d_in[6];
    const float* Wo   = (const float*)d_in[7];
    const float* Wg   = (const float*)d_in[8];
    const float* bg   = (const float*)d_in[9];
    const float* Wvsa = (const float*)d_in[10];
    const float* R    = (const float*)d_in[11];

    const int nK = HN * NBUCKET * ASSOC * DKEY;   // 4,194,304
    const int nV = HN * NBUCKET * ASSOC * DVAL;   // 8,388,608
    const int nT = HN * NBUCKET * ASSOC * DTAG;   // 2,097,152

    float* y_out = (float*)d_out;
    float* K_out = y_out + (size_t)NTOK * DMODEL;
    float* V_out = K_out + nK;
    float* T_out = V_out + nV;

    float* qw    = (float*)d_ws;                       // [NTOK][128] qkey|wkey
    float* wvalg = qw    + (size_t)NTOK * 128;         // [NTOK][128]
    float* readw = wvalg + (size_t)NTOK * 128;         // [NTOK][128]
    float* gatep = readw + (size_t)NTOK * 128;         // [8][NTOK] gate partials
    // ws usage ~ 25.7 MB

    // split-K partials live in d_out's y region (overwritten later by y-GEMM):
    //   qw partials: [8][NTOK][128] floats = 67.1 MB = exactly the y region
    //   wval partials: [4][NTOK][128] = 33.5 MB, reuses the same region after reduce8
    float* part = y_out;

    // 1) qkey|wkey projection (fp32, 64x128 tile, split-K=8, fused gate partials)
    gemm_f32_64<<<dim3(NTOK / 64, 1, 8), 256, 0, stream>>>(u, Wq, Wwk, Wg, part, gatep);
    reduce8_kernel<<<(NTOK * 128 / 4 + 255) / 256, 256, 0, stream>>>(part, qw, NTOK * 128 / 4, NTOK * 128 / 4);

    // 2) wval projection (bf16 MFMA, split-K=4, partials reuse y region)
    gemm_wval_splitk<<<dim3(NTOK / 128, 4), 256, 0, stream>>>(u, Wv, part);
    reduce4_kernel<<<(NTOK * 128 / 4 + 255) / 256, 256, 0, stream>>>(part, wvalg, NTOK * 128 / 4, NTOK * 128 / 4);

    // 3) seed outputs with pristine memories
    hipMemcpyAsync(K_out, memK, (size_t)nK * 4, hipMemcpyDeviceToDevice, stream);
    hipMemcpyAsync(V_out, memV, (size_t)nV * 4, hipMemcpyDeviceToDevice, stream);
    hipMemcpyAsync(T_out, memT, (size_t)nT * 4, hipMemcpyDeviceToDevice, stream);

    // 4) fused routing / gather / score / read / scatter (atomics into d_out)
    route_kernel<<<NTOK / 4, 256, 0, stream>>>(memK, memV, memT, R, Wvsa,
                                               qw, wvalg, gatep, bg,
                                               K_out, V_out, T_out, readw);

    // 5) y = read @ Wo^T (bf16 MFMA)
    gemm_mfma<<<dim3(NTOK / 128, DMODEL / 128), 256, 0, stream>>>(readw, Wo, y_out, NTOK, DMODEL, DVAL);
}

// Round 6
// 401.257 us; speedup vs baseline: 1.2288x; 1.1200x over previous
//
#include <hip/hip_runtime.h>
#include <hip/hip_bf16.h>
#include <math.h>

#define NTOK    16384
#define DMODEL  1024
#define HN      4
#define NBUCKET 4096
#define ASSOC   4
#define DKEY    64
#define DVAL    128
#define DTAG    32
#define NBITS   12
#define EPSV    1e-6f

typedef __bf16 bf16x8 __attribute__((ext_vector_type(8)));
typedef float  f32x4  __attribute__((ext_vector_type(4)));
typedef float  f32x2  __attribute__((ext_vector_type(2)));

__device__ __forceinline__ unsigned short f2bf_raw(float f) {
    __hip_bfloat16 h = __float2bfloat16(f);
    return *(unsigned short*)&h;
}

// ---------------- MFMA GEMM 128x128 tile: C[M,N] = A[M,K] @ B[N,K]^T ----------------
__global__ __launch_bounds__(256) void gemm_mfma(const float* __restrict__ A,
                                                 const float* __restrict__ B,
                                                 float* __restrict__ C,
                                                 int M, int N, int K) {
    __shared__ __align__(16) unsigned short As[4][128][8];
    __shared__ __align__(16) unsigned short Bs[4][128][8];
    const int t    = threadIdx.x;
    const int lane = t & 63;
    const int w    = t >> 6;
    const int wm   = (w & 1) * 64;
    const int wn   = (w >> 1) * 64;
    const int bm   = blockIdx.x * 128;
    const int bn   = blockIdx.y * 128;

    const int srow = t & 127;
    const int skg  = t >> 7;
    const float* Ap = A + (size_t)(bm + srow) * K;
    const float* Bp = B + (size_t)(bn + srow) * K;

    const int fr = lane & 15;
    const int kq = lane >> 4;

    f32x4 acc[4][4] = {};

    for (int k0 = 0; k0 < K; k0 += 32) {
        #pragma unroll
        for (int ii = 0; ii < 2; ++ii) {
            const int kg = skg + ii * 2;
            const float4 a0 = *(const float4*)(Ap + k0 + kg * 8);
            const float4 a1 = *(const float4*)(Ap + k0 + kg * 8 + 4);
            const float4 b0 = *(const float4*)(Bp + k0 + kg * 8);
            const float4 b1 = *(const float4*)(Bp + k0 + kg * 8 + 4);
            unsigned short* da = &As[kg][srow][0];
            da[0] = f2bf_raw(a0.x); da[1] = f2bf_raw(a0.y);
            da[2] = f2bf_raw(a0.z); da[3] = f2bf_raw(a0.w);
            da[4] = f2bf_raw(a1.x); da[5] = f2bf_raw(a1.y);
            da[6] = f2bf_raw(a1.z); da[7] = f2bf_raw(a1.w);
            unsigned short* db = &Bs[kg][srow][0];
            db[0] = f2bf_raw(b0.x); db[1] = f2bf_raw(b0.y);
            db[2] = f2bf_raw(b0.z); db[3] = f2bf_raw(b0.w);
            db[4] = f2bf_raw(b1.x); db[5] = f2bf_raw(b1.y);
            db[6] = f2bf_raw(b1.z); db[7] = f2bf_raw(b1.w);
        }
        __syncthreads();
        bf16x8 af[4], bfv[4];
        #pragma unroll
        for (int i = 0; i < 4; ++i) af[i]  = *(const bf16x8*)&As[kq][wm + i * 16 + fr][0];
        #pragma unroll
        for (int j = 0; j < 4; ++j) bfv[j] = *(const bf16x8*)&Bs[kq][wn + j * 16 + fr][0];
        #pragma unroll
        for (int i = 0; i < 4; ++i)
            #pragma unroll
            for (int j = 0; j < 4; ++j)
                acc[i][j] = __builtin_amdgcn_mfma_f32_16x16x32_bf16(af[i], bfv[j], acc[i][j], 0, 0, 0);
        __syncthreads();
    }
    #pragma unroll
    for (int i = 0; i < 4; ++i)
        #pragma unroll
        for (int j = 0; j < 4; ++j)
            #pragma unroll
            for (int r = 0; r < 4; ++r)
                C[(size_t)(bm + wm + i * 16 + kq * 4 + r) * N + (bn + wn + j * 16 + fr)] = acc[i][j][r];
}

// ---------------- wval: MFMA 128x128 tile, split-K over blockIdx.y ----------------
// Cpart[kz][NTOK][128] = u[128-tile, kz-quarter] @ Wv[:, kz-quarter]^T
__global__ __launch_bounds__(256) void gemm_wval_splitk(const float* __restrict__ A,
                                                        const float* __restrict__ B,
                                                        float* __restrict__ Cpart) {
    __shared__ __align__(16) unsigned short As[4][128][8];
    __shared__ __align__(16) unsigned short Bs[4][128][8];
    const int t    = threadIdx.x;
    const int lane = t & 63;
    const int w    = t >> 6;
    const int wm   = (w & 1) * 64;
    const int wn   = (w >> 1) * 64;
    const int bm   = blockIdx.x * 128;
    const int kz   = blockIdx.y;
    const int kbeg = kz * 256;

    const int srow = t & 127;
    const int skg  = t >> 7;
    const float* Ap = A + (size_t)(bm + srow) * DMODEL;
    const float* Bp = B + (size_t)srow * DMODEL;

    const int fr = lane & 15;
    const int kq = lane >> 4;

    f32x4 acc[4][4] = {};

    for (int k0 = kbeg; k0 < kbeg + 256; k0 += 32) {
        #pragma unroll
        for (int ii = 0; ii < 2; ++ii) {
            const int kg = skg + ii * 2;
            const float4 a0 = *(const float4*)(Ap + k0 + kg * 8);
            const float4 a1 = *(const float4*)(Ap + k0 + kg * 8 + 4);
            const float4 b0 = *(const float4*)(Bp + k0 + kg * 8);
            const float4 b1 = *(const float4*)(Bp + k0 + kg * 8 + 4);
            unsigned short* da = &As[kg][srow][0];
            da[0] = f2bf_raw(a0.x); da[1] = f2bf_raw(a0.y);
            da[2] = f2bf_raw(a0.z); da[3] = f2bf_raw(a0.w);
            da[4] = f2bf_raw(a1.x); da[5] = f2bf_raw(a1.y);
            da[6] = f2bf_raw(a1.z); da[7] = f2bf_raw(a1.w);
            unsigned short* db = &Bs[kg][srow][0];
            db[0] = f2bf_raw(b0.x); db[1] = f2bf_raw(b0.y);
            db[2] = f2bf_raw(b0.z); db[3] = f2bf_raw(b0.w);
            db[4] = f2bf_raw(b1.x); db[5] = f2bf_raw(b1.y);
            db[6] = f2bf_raw(b1.z); db[7] = f2bf_raw(b1.w);
        }
        __syncthreads();
        bf16x8 af[4], bfv[4];
        #pragma unroll
        for (int i = 0; i < 4; ++i) af[i]  = *(const bf16x8*)&As[kq][wm + i * 16 + fr][0];
        #pragma unroll
        for (int j = 0; j < 4; ++j) bfv[j] = *(const bf16x8*)&Bs[kq][wn + j * 16 + fr][0];
        #pragma unroll
        for (int i = 0; i < 4; ++i)
            #pragma unroll
            for (int j = 0; j < 4; ++j)
                acc[i][j] = __builtin_amdgcn_mfma_f32_16x16x32_bf16(af[i], bfv[j], acc[i][j], 0, 0, 0);
        __syncthreads();
    }
    float* Cp = Cpart + (size_t)kz * NTOK * 128;
    #pragma unroll
    for (int i = 0; i < 4; ++i)
        #pragma unroll
        for (int j = 0; j < 4; ++j)
            #pragma unroll
            for (int r = 0; r < 4; ++r)
                Cp[(size_t)(bm + wm + i * 16 + kq * 4 + r) * 128 + (wn + j * 16 + fr)] = acc[i][j][r];
}

// ---------------- fp32 GEMM split-K=4 (round-1 proven): Cpart[z][M,128] ----------
__global__ __launch_bounds__(256) void gemm_f32_splitk(const float* __restrict__ A,
                                                       const float* __restrict__ B,
                                                       float* __restrict__ Cpart,
                                                       int M, int K, int K_quarter) {
    __shared__ __align__(16) float As[2][16][68];
    __shared__ __align__(16) float Bs[2][16][140];
    const int t  = threadIdx.x;
    const int bm = blockIdx.x * 64;
    const int kz = blockIdx.z;
    const int tx = t & 15;
    const int ty = t >> 4;

    const int arow = t >> 2, ac = (t & 3) * 4;
    const int brow = t >> 1, bc = (t & 1) * 8;
    const int bperm = brow + ((brow >> 5) << 2);
    const int goff  = tx * 8 + ((tx >> 2) << 2);

    const float* Apt = A + (size_t)(bm + arow) * K + ac;
    const float* Bpt = B + (size_t)brow * K + bc;

    const int kbeg = kz * K_quarter;
    const int NSTEP = 16;              // K_quarter = 256, 16 k per step

    f32x2 acc2[4][4] = {};

    float4 av = *(const float4*)(Apt + kbeg);
    float4 b0 = *(const float4*)(Bpt + kbeg);
    float4 b1 = *(const float4*)(Bpt + kbeg + 4);
    As[0][ac + 0][arow] = av.x; As[0][ac + 1][arow] = av.y;
    As[0][ac + 2][arow] = av.z; As[0][ac + 3][arow] = av.w;
    Bs[0][bc + 0][bperm] = b0.x; Bs[0][bc + 1][bperm] = b0.y;
    Bs[0][bc + 2][bperm] = b0.z; Bs[0][bc + 3][bperm] = b0.w;
    Bs[0][bc + 4][bperm] = b1.x; Bs[0][bc + 5][bperm] = b1.y;
    Bs[0][bc + 6][bperm] = b1.z; Bs[0][bc + 7][bperm] = b1.w;
    __syncthreads();

    for (int s = 0; s < NSTEP; ++s) {
        const int cur = s & 1;
        if (s + 1 < NSTEP) {
            const int k0 = kbeg + (s + 1) * 16;
            av = *(const float4*)(Apt + k0);
            b0 = *(const float4*)(Bpt + k0);
            b1 = *(const float4*)(Bpt + k0 + 4);
        }
        #pragma unroll
        for (int kk = 0; kk < 16; ++kk) {
            const float4 a4 = *(const float4*)&As[cur][kk][ty * 4];
            const float4 v0 = *(const float4*)&Bs[cur][kk][goff];
            const float4 v1 = *(const float4*)&Bs[cur][kk][goff + 4];
            const float aa[4] = {a4.x, a4.y, a4.z, a4.w};
            const f32x2 bb[4] = {{v0.x, v0.y}, {v0.z, v0.w}, {v1.x, v1.y}, {v1.z, v1.w}};
            #pragma unroll
            for (int i = 0; i < 4; ++i) {
                const f32x2 as2 = {aa[i], aa[i]};
                #pragma unroll
                for (int j = 0; j < 4; ++j)
                    acc2[i][j] = __builtin_elementwise_fma(as2, bb[j], acc2[i][j]);
            }
        }
        if (s + 1 < NSTEP) {
            const int nb = cur ^ 1;
            As[nb][ac + 0][arow] = av.x; As[nb][ac + 1][arow] = av.y;
            As[nb][ac + 2][arow] = av.z; As[nb][ac + 3][arow] = av.w;
            Bs[nb][bc + 0][bperm] = b0.x; Bs[nb][bc + 1][bperm] = b0.y;
            Bs[nb][bc + 2][bperm] = b0.z; Bs[nb][bc + 3][bperm] = b0.w;
            Bs[nb][bc + 4][bperm] = b1.x; Bs[nb][bc + 5][bperm] = b1.y;
            Bs[nb][bc + 6][bperm] = b1.z; Bs[nb][bc + 7][bperm] = b1.w;
        }
        __syncthreads();
    }

    float* Cp = Cpart + (size_t)kz * M * 128;
    #pragma unroll
    for (int i = 0; i < 4; ++i) {
        float4 o0, o1;
        o0.x = acc2[i][0].x; o0.y = acc2[i][0].y; o0.z = acc2[i][1].x; o0.w = acc2[i][1].y;
        o1.x = acc2[i][2].x; o1.y = acc2[i][2].y; o1.z = acc2[i][3].x; o1.w = acc2[i][3].y;
        float* dst = &Cp[(size_t)(bm + ty * 4 + i) * 128 + tx * 8];
        *(float4*)dst       = o0;
        *(float4*)(dst + 4) = o1;
    }
}

// ---------------- fused routing / gather / score / read / scatter ----------------
// v2: inlines reduce4(qw partials), reduce4(wval partials), and the gate dot.
__global__ __launch_bounds__(256) void route_kernel(
    const float* __restrict__ memK, const float* __restrict__ memV,
    const float* __restrict__ memT, const float* __restrict__ R,
    const float* __restrict__ Wvsa,
    const float* __restrict__ partQ, const float* __restrict__ partW,
    const float* __restrict__ u, const float* __restrict__ Wg,
    const float* __restrict__ bg,
    float* __restrict__ accK, float* __restrict__ accV, float* __restrict__ accT,
    float* __restrict__ readw) {
    __shared__ float sQK[4][64], sWK[4][64], sQT[4][32], sWT[4][32];
    __shared__ float sSc[4][16], sSim[4][16], sTsim[4][16], sW[4][16];
    __shared__ int   sIdx[4][4], sAst[4][4];
    __shared__ float sEff[4][4];

    const int wv = threadIdx.x >> 6;
    const int lane = threadIdx.x & 63;
    const int n = blockIdx.x * 4 + wv;
    const size_t PZ = (size_t)NTOK * 128;    // stride between split-K partials

    // inline reduce4 of qw partials (same pairwise order as reduce4_kernel)
    const size_t qb = (size_t)n * 128;
    const float qk = (partQ[qb + lane]          + partQ[PZ + qb + lane])
                   + (partQ[2 * PZ + qb + lane] + partQ[3 * PZ + qb + lane]);
    const float wk = (partQ[qb + 64 + lane]          + partQ[PZ + qb + 64 + lane])
                   + (partQ[2 * PZ + qb + 64 + lane] + partQ[3 * PZ + qb + 64 + lane]);
    sQK[wv][lane] = qk;
    sWK[wv][lane] = wk;
    float wk2 = wk * wk;
    #pragma unroll
    for (int off = 1; off < 64; off <<= 1) wk2 += __shfl_xor(wk2, off);
    const float wknorm = sqrtf(wk2) + EPSV;

    // inline gate: identical arithmetic/order to the old gate_kernel
    float gacc = 0.f;
    {
        const float* up = u + (size_t)n * DMODEL;
        #pragma unroll
        for (int j = 0; j < 16; ++j)
            gacc += up[lane + 64 * j] * Wg[lane + 64 * j];
        #pragma unroll
        for (int off = 1; off < 64; off <<= 1) gacc += __shfl_xor(gacc, off);
    }
    const float gate = 1.f / (1.f + expf(-(gacc + bg[0])));
    __syncthreads();

    {
        const int tg = lane & 31;
        const float* keyp = (lane < 32) ? sQK[wv] : sWK[wv];
        float tacc = 0.f;
        for (int d = 0; d < 64; ++d) tacc += keyp[d] * Wvsa[d * DTAG + tg];
        const float tagv = tanhf(tacc);
        if (lane < 32) sQT[wv][tg] = tagv; else sWT[wv][tg] = tagv;
        float wt2 = (lane >= 32) ? tagv * tagv : 0.f;
        #pragma unroll
        for (int off = 1; off < 64; off <<= 1) wt2 += __shfl_xor(wt2, off);
        const float wtnorm = sqrtf(wt2) + EPSV;

        bool bit = false;
        if (lane < 48) {
            const int h = lane / 12, k = lane % 12;
            float bacc = 0.f;
            for (int d = 0; d < 64; ++d)
                bacc += sQK[wv][d] * R[(size_t)(h * DKEY + d) * NBITS + k];
            bit = bacc > 0.f;
        }
        const unsigned long long mask = __ballot(bit);
        if (lane < 4) sIdx[wv][lane] = (int)((mask >> (12 * lane)) & 0xFFFull);
        __syncthreads();

        const int slot = lane >> 2, sub = lane & 3;
        const int sh = slot >> 2, sa = slot & 3;
        const int rowS = (sh * NBUCKET + sIdx[wv][sh]) * ASSOC + sa;
        const float* Kp = memK + (size_t)rowS * DKEY;
        const float* Tp = memT + (size_t)rowS * DTAG;
        float d_qk = 0, d_wk = 0, d_kk = 0, d_qt = 0, d_wt = 0, d_tt = 0;
        for (int j = 0; j < 16; ++j) {
            const int d = sub * 16 + j;
            const float kv = Kp[d];
            d_qk += sQK[wv][d] * kv;
            d_wk += sWK[wv][d] * kv;
            d_kk += kv * kv;
        }
        for (int j = 0; j < 8; ++j) {
            const int d = sub * 8 + j;
            const float tv = Tp[d];
            d_qt += sQT[wv][d] * tv;
            d_wt += sWT[wv][d] * tv;
            d_tt += tv * tv;
        }
        #pragma unroll
        for (int off = 1; off <= 2; off <<= 1) {
            d_qk += __shfl_xor(d_qk, off);
            d_wk += __shfl_xor(d_wk, off);
            d_kk += __shfl_xor(d_kk, off);
            d_qt += __shfl_xor(d_qt, off);
            d_wt += __shfl_xor(d_wt, off);
            d_tt += __shfl_xor(d_tt, off);
        }
        if (sub == 0) {
            sSc[wv][slot]   = d_qk * 0.125f + d_qt * 0.17677669529663687f;
            sSim[wv][slot]  = d_wk / (wknorm * (sqrtf(d_kk) + EPSV));
            sTsim[wv][slot] = d_wt / (wtnorm * (sqrtf(d_tt) + EPSV));
        }
    }
    __syncthreads();

    if (lane < 16) {
        const float sc = sSc[wv][lane];
        float m = sc;
        #pragma unroll
        for (int off = 1; off < 16; off <<= 1) m = fmaxf(m, __shfl_xor(m, off, 16));
        const float e = expf(sc - m);
        float ssum = e;
        #pragma unroll
        for (int off = 1; off < 16; off <<= 1) ssum += __shfl_xor(ssum, off, 16);
        sW[wv][lane] = e / ssum;
    }
    if (lane < 4) {
        float bs = -1e30f; int as = 0; float mt = -1e30f;
        #pragma unroll
        for (int aa = 0; aa < 4; ++aa) {
            const float sv = sSim[wv][lane * 4 + aa];
            if (sv > bs) { bs = sv; as = aa; }
            mt = fmaxf(mt, sTsim[wv][lane * 4 + aa]);
        }
        const float novelty = 1.f - mt;
        float e = 0.1f * gate;
        if (!(gate > 0.5f) || !(bs >= 0.f) || !(novelty >= 0.f)) e = 0.f;
        sEff[wv][lane] = e;
        sAst[wv][lane] = as;
    }
    __syncthreads();

    float r0 = 0.f, r1 = 0.f;
    #pragma unroll
    for (int s2 = 0; s2 < 16; ++s2) {
        const int hh = s2 >> 2, aa = s2 & 3;
        const int rw = (hh * NBUCKET + sIdx[wv][hh]) * ASSOC + aa;
        const float wgt = sW[wv][s2];
        const float* Vp = memV + (size_t)rw * DVAL;
        r0 += wgt * Vp[lane];
        r1 += wgt * Vp[64 + lane];
    }
    readw[(size_t)n * DVAL + lane]      = r0;
    readw[(size_t)n * DVAL + 64 + lane] = r1;

    // inline reduce4 of wval partials (same pairwise order as reduce4_kernel)
    const float wv0 = (partW[qb + lane]          + partW[PZ + qb + lane])
                    + (partW[2 * PZ + qb + lane] + partW[3 * PZ + qb + lane]);
    const float wv1 = (partW[qb + 64 + lane]          + partW[PZ + qb + 64 + lane])
                    + (partW[2 * PZ + qb + 64 + lane] + partW[3 * PZ + qb + 64 + lane]);
    for (int hh = 0; hh < 4; ++hh) {
        const float e = sEff[wv][hh];
        if (e == 0.f) continue;
        const int rw = (hh * NBUCKET + sIdx[wv][hh]) * ASSOC + sAst[wv][hh];
        atomicAdd(&accK[(size_t)rw * DKEY + lane],
                  e * (sWK[wv][lane] - memK[(size_t)rw * DKEY + lane]));
        atomicAdd(&accV[(size_t)rw * DVAL + lane],
                  e * (wv0 - memV[(size_t)rw * DVAL + lane]));
        atomicAdd(&accV[(size_t)rw * DVAL + 64 + lane],
                  e * (wv1 - memV[(size_t)rw * DVAL + 64 + lane]));
        if (lane < 32)
            atomicAdd(&accT[(size_t)rw * DTAG + lane],
                      e * (sWT[wv][lane] - memT[(size_t)rw * DTAG + lane]));
    }
}

// ---------------- launcher ----------------
extern "C" void kernel_launch(void* const* d_in, const int* in_sizes, int n_in,
                              void* d_out, int out_size, void* d_ws, size_t ws_size,
                              hipStream_t stream) {
    const float* u    = (const float*)d_in[0];
    const float* memK = (const float*)d_in[1];
    const float* memV = (const float*)d_in[2];
    const float* memT = (const float*)d_in[3];
    const float* Wq   = (const float*)d_in[4];
    const float* Wwk  = (const float*)d_in[5];
    const float* Wv   = (const float*)d_in[6];
    const float* Wo   = (const float*)d_in[7];
    const float* Wg   = (const float*)d_in[8];
    const float* bg   = (const float*)d_in[9];
    const float* Wvsa = (const float*)d_in[10];
    const float* R    = (const float*)d_in[11];

    const int nK = HN * NBUCKET * ASSOC * DKEY;   // 4,194,304
    const int nV = HN * NBUCKET * ASSOC * DVAL;   // 8,388,608
    const int nT = HN * NBUCKET * ASSOC * DTAG;   // 2,097,152

    float* y_out = (float*)d_out;
    float* K_out = y_out + (size_t)NTOK * DMODEL;
    float* V_out = K_out + nK;
    float* T_out = V_out + nV;

    float* readw = (float*)d_ws;                       // [NTOK][128]
    float* qwW   = readw + (size_t)NTOK * 128;         // [128][1024] cat(Wq,Wwk)
    // ws usage ~ 8.9 MB (well under proven 25.8 MB)

    // Both split-K partial sets live in d_out's y region SIMULTANEOUSLY
    // (consumed by route, then overwritten by the y-GEMM):
    //   partQ [4][NTOK][128] = 33.55 MB at offset 0
    //   partW [4][NTOK][128] = 33.55 MB at offset 33.55 MB   (total = y region exactly)
    float* partQ = y_out;
    float* partW = y_out + (size_t)4 * NTOK * 128;

    // 0) concat routing weights
    hipMemcpyAsync(qwW,          Wq,  (size_t)DKEY * DMODEL * 4, hipMemcpyDeviceToDevice, stream);
    hipMemcpyAsync(qwW + 65536,  Wwk, (size_t)DKEY * DMODEL * 4, hipMemcpyDeviceToDevice, stream);

    // 1) qkey|wkey projection (fp32, round-1 proven kernel, split-K=4)
    gemm_f32_splitk<<<dim3(NTOK / 64, 1, 4), 256, 0, stream>>>(u, qwW, partQ, NTOK, DMODEL, DMODEL / 4);

    // 2) wval projection (bf16 MFMA, split-K=4)
    gemm_wval_splitk<<<dim3(NTOK / 128, 4), 256, 0, stream>>>(u, Wv, partW);

    // 3) seed outputs with pristine memories
    hipMemcpyAsync(K_out, memK, (size_t)nK * 4, hipMemcpyDeviceToDevice, stream);
    hipMemcpyAsync(V_out, memV, (size_t)nV * 4, hipMemcpyDeviceToDevice, stream);
    hipMemcpyAsync(T_out, memT, (size_t)nT * 4, hipMemcpyDeviceToDevice, stream);

    // 4) fused routing / gather / score / read / scatter
    //    (also sums both partial sets inline + computes the gate)
    route_kernel<<<NTOK / 4, 256, 0, stream>>>(memK, memV, memT, R, Wvsa,
                                               partQ, partW, u, Wg, bg,
                                               K_out, V_out, T_out, readw);

    // 5) y = read @ Wo^T (bf16 MFMA)
    gemm_mfma<<<dim3(NTOK / 128, DMODEL / 128), 256, 0, stream>>>(readw, Wo, y_out, NTOK, DMODEL, DVAL);
}